// Round 5
// baseline (64.127 us; speedup 1.0000x reference)
//
#include <hip/hip_runtime.h>
#include <hip/hip_bf16.h>

// Inverse pose: in[b] = [R | t] (3x4 row-major), out[b] = [R^T | -R^T t].
// v4: wave-local LDS exchange — each wave owns a 3KB LDS region and stages
// its own 64 poses, so NO __syncthreads at all (CDNA waves are lockstep;
// same-wave DS ops are processed in order). Non-temporal loads AND stores:
// both streams are touch-once within a dispatch.

typedef float f32x4 __attribute__((ext_vector_type(4)));

__global__ __launch_bounds__(256) void inverse_pose_wave(
    const f32x4* __restrict__ in, f32x4* __restrict__ out) {
    __shared__ f32x4 s[256 * 3];  // 12 KB; 4 waves x 192 float4 regions

    const int t = threadIdx.x;
    const int w = t >> 6;         // wave id 0..3
    const int l = t & 63;         // lane 0..63
    const int wbase = w * 192;    // wave's private LDS region (float4 units)
    const int gbase = blockIdx.x * 768 + wbase;  // max 12M, fits int

    // Dense coalesced nt loads (1KB per instruction per wave).
    const f32x4 r0 = __builtin_nontemporal_load(&in[gbase + l]);
    const f32x4 r1 = __builtin_nontemporal_load(&in[gbase + l + 64]);
    const f32x4 r2 = __builtin_nontemporal_load(&in[gbase + l + 128]);
    s[wbase + l]       = r0;
    s[wbase + l + 64]  = r1;
    s[wbase + l + 128] = r2;

    // Wave-local gather: lane l takes pose l of this wave's region.
    // (stride-12 f32x4: 8 lanes cover all 32 banks -> conflict-free; DS unit
    // processes this wave's write->read in order, no barrier needed.)
    const f32x4 a0 = s[wbase + 3 * l + 0];
    const f32x4 a1 = s[wbase + 3 * l + 1];
    const f32x4 a2 = s[wbase + 3 * l + 2];

    f32x4 o0, o1, o2;
    o0.x = a0.x; o0.y = a1.x; o0.z = a2.x;
    o1.x = a0.y; o1.y = a1.y; o1.z = a2.y;
    o2.x = a0.z; o2.y = a1.z; o2.z = a2.z;
    o0.w = -(a0.x * a0.w + a1.x * a1.w + a2.x * a2.w);
    o1.w = -(a0.y * a0.w + a1.y * a1.w + a2.y * a2.w);
    o2.w = -(a0.z * a0.w + a1.z * a1.w + a2.z * a2.w);

    // In-place scatter back (all lanes' reads above precede these writes in
    // wave program order), then dense reads + dense nt stores.
    s[wbase + 3 * l + 0] = o0;
    s[wbase + 3 * l + 1] = o1;
    s[wbase + 3 * l + 2] = o2;

    __builtin_nontemporal_store(s[wbase + l],       &out[gbase + l]);
    __builtin_nontemporal_store(s[wbase + l + 64],  &out[gbase + l + 64]);
    __builtin_nontemporal_store(s[wbase + l + 128], &out[gbase + l + 128]);
}

// Tail fallback (unused at B=4M; 4,000,000 % 256 == 0).
__global__ __launch_bounds__(256) void inverse_pose_tail(
    const f32x4* __restrict__ in, f32x4* __restrict__ out,
    int first_pose, int n_poses) {
    const int i = first_pose + blockIdx.x * blockDim.x + threadIdx.x;
    if (i >= n_poses) return;
    const f32x4 a0 = in[i * 3 + 0];
    const f32x4 a1 = in[i * 3 + 1];
    const f32x4 a2 = in[i * 3 + 2];
    f32x4 o0, o1, o2;
    o0.x = a0.x; o0.y = a1.x; o0.z = a2.x;
    o1.x = a0.y; o1.y = a1.y; o1.z = a2.y;
    o2.x = a0.z; o2.y = a1.z; o2.z = a2.z;
    o0.w = -(a0.x * a0.w + a1.x * a1.w + a2.x * a2.w);
    o1.w = -(a0.y * a0.w + a1.y * a1.w + a2.y * a2.w);
    o2.w = -(a0.z * a0.w + a1.z * a1.w + a2.z * a2.w);
    out[i * 3 + 0] = o0;
    out[i * 3 + 1] = o1;
    out[i * 3 + 2] = o2;
}

extern "C" void kernel_launch(void* const* d_in, const int* in_sizes, int n_in,
                              void* d_out, int out_size, void* d_ws, size_t ws_size,
                              hipStream_t stream) {
    const f32x4* in = (const f32x4*)d_in[0];
    f32x4* out = (f32x4*)d_out;
    const int n_poses = in_sizes[0] / 12;  // 4,000,000

    const int full_blocks = n_poses / 256;  // 15625 exactly at B=4M
    const int rem = n_poses % 256;

    if (full_blocks > 0)
        inverse_pose_wave<<<full_blocks, 256, 0, stream>>>(in, out);
    if (rem > 0) {
        const int first = full_blocks * 256;
        inverse_pose_tail<<<(rem + 255) / 256, 256, 0, stream>>>(in, out, first, n_poses);
    }
}

// Round 6
// 60.029 us; speedup vs baseline: 1.0683x; 1.0683x over previous
//
#include <hip/hip_runtime.h>
#include <hip/hip_bf16.h>

// Inverse pose: in[b] = [R | t] (3x4 row-major), out[b] = [R^T | -R^T t].
// v5: wave-local LDS exchange (no __syncthreads; same-wave DS ops are
// in-order) + CACHEABLE loads (input is re-read each graph replay — L3
// serves ~half of it; nt loads broke that in v4) + non-temporal stores
// (output truly is touch-once; keep it from evicting input from L3).

typedef float f32x4 __attribute__((ext_vector_type(4)));

__global__ __launch_bounds__(256) void inverse_pose_wave(
    const f32x4* __restrict__ in, f32x4* __restrict__ out) {
    __shared__ f32x4 s[256 * 3];  // 12 KB; 4 waves x 192 float4 regions

    const int t = threadIdx.x;
    const int w = t >> 6;         // wave id 0..3
    const int l = t & 63;         // lane 0..63
    const int wbase = w * 192;    // wave's private LDS region (float4 units)
    const int gbase = blockIdx.x * 768 + wbase;  // max 12M, fits int

    // Dense coalesced cacheable loads (1KB per instruction per wave).
    const f32x4 r0 = in[gbase + l];
    const f32x4 r1 = in[gbase + l + 64];
    const f32x4 r2 = in[gbase + l + 128];
    s[wbase + l]       = r0;
    s[wbase + l + 64]  = r1;
    s[wbase + l + 128] = r2;

    // Wave-local gather: lane l takes pose l of this wave's region.
    // (stride-12 f32x4: 8 lanes cover all 32 banks -> conflict-free; DS unit
    // processes this wave's write->read in order, no barrier needed.)
    const f32x4 a0 = s[wbase + 3 * l + 0];
    const f32x4 a1 = s[wbase + 3 * l + 1];
    const f32x4 a2 = s[wbase + 3 * l + 2];

    f32x4 o0, o1, o2;
    o0.x = a0.x; o0.y = a1.x; o0.z = a2.x;
    o1.x = a0.y; o1.y = a1.y; o1.z = a2.y;
    o2.x = a0.z; o2.y = a1.z; o2.z = a2.z;
    o0.w = -(a0.x * a0.w + a1.x * a1.w + a2.x * a2.w);
    o1.w = -(a0.y * a0.w + a1.y * a1.w + a2.y * a2.w);
    o2.w = -(a0.z * a0.w + a1.z * a1.w + a2.z * a2.w);

    // In-place scatter back (wave program order guarantees reads above
    // completed issue before these writes), then dense reads + nt stores.
    s[wbase + 3 * l + 0] = o0;
    s[wbase + 3 * l + 1] = o1;
    s[wbase + 3 * l + 2] = o2;

    __builtin_nontemporal_store(s[wbase + l],       &out[gbase + l]);
    __builtin_nontemporal_store(s[wbase + l + 64],  &out[gbase + l + 64]);
    __builtin_nontemporal_store(s[wbase + l + 128], &out[gbase + l + 128]);
}

// Tail fallback (unused at B=4M; 4,000,000 % 256 == 0).
__global__ __launch_bounds__(256) void inverse_pose_tail(
    const f32x4* __restrict__ in, f32x4* __restrict__ out,
    int first_pose, int n_poses) {
    const int i = first_pose + blockIdx.x * blockDim.x + threadIdx.x;
    if (i >= n_poses) return;
    const f32x4 a0 = in[i * 3 + 0];
    const f32x4 a1 = in[i * 3 + 1];
    const f32x4 a2 = in[i * 3 + 2];
    f32x4 o0, o1, o2;
    o0.x = a0.x; o0.y = a1.x; o0.z = a2.x;
    o1.x = a0.y; o1.y = a1.y; o1.z = a2.y;
    o2.x = a0.z; o2.y = a1.z; o2.z = a2.z;
    o0.w = -(a0.x * a0.w + a1.x * a1.w + a2.x * a2.w);
    o1.w = -(a0.y * a0.w + a1.y * a1.w + a2.y * a2.w);
    o2.w = -(a0.z * a0.w + a1.z * a1.w + a2.z * a2.w);
    out[i * 3 + 0] = o0;
    out[i * 3 + 1] = o1;
    out[i * 3 + 2] = o2;
}

extern "C" void kernel_launch(void* const* d_in, const int* in_sizes, int n_in,
                              void* d_out, int out_size, void* d_ws, size_t ws_size,
                              hipStream_t stream) {
    const f32x4* in = (const f32x4*)d_in[0];
    f32x4* out = (f32x4*)d_out;
    const int n_poses = in_sizes[0] / 12;  // 4,000,000

    const int full_blocks = n_poses / 256;  // 15625 exactly at B=4M
    const int rem = n_poses % 256;

    if (full_blocks > 0)
        inverse_pose_wave<<<full_blocks, 256, 0, stream>>>(in, out);
    if (rem > 0) {
        const int first = full_blocks * 256;
        inverse_pose_tail<<<(rem + 255) / 256, 256, 0, stream>>>(in, out, first, n_poses);
    }
}